// Round 9
// baseline (232.323 us; speedup 1.0000x reference)
//
#include <hip/hip_runtime.h>
#include <hip/hip_bf16.h>

#define BB 8
#define LL 4096
#define NCH 8192
#define IDIM 256
#define KDIM 512
#define ODIM 512
#define NDIR 6
#define TOT (BB * LL)  // 32768

// Per-dir fixed-capacity buckets (expected ~5461/dir; 8192 = huge headroom).
#define CAP 8192
#define IDX_OFF 64
#define ROWS_OFF (64 + 8 * CAP)
#define WS_W_OFF (64 + 16 * CAP)
#define W_ELEMS (NDIR * ODIM * KDIM)  // 1,572,864
#define N_W8 (W_ELEMS / 8)            // 196,608 -> 768 blocks

// gemm grid: 2 n-pairs x 262 m-tiles = 524 blocks (bijective XCD swizzle,
// 524 = 8*65+4 -> chunks of 66/65).
#define NWG 524

typedef short short8 __attribute__((ext_vector_type(8)));
typedef float floatx4 __attribute__((ext_vector_type(4)));

__device__ inline void async_copy16(const void* g, void* l) {
  __builtin_amdgcn_global_load_lds(
      (const __attribute__((address_space(1))) void*)g,
      (__attribute__((address_space(3))) void*)l, 16, 0, 0);
}

__device__ inline void cvt8(const float* __restrict__ src,
                            __hip_bfloat16* __restrict__ dst, int i) {
  const floatx4* s = (const floatx4*)src;
  floatx4 a = s[2 * i];
  floatx4 b = s[2 * i + 1];
  union { short8 v; __hip_bfloat16 h[8]; } u;
  u.h[0] = __float2bfloat16(a[0]); u.h[1] = __float2bfloat16(a[1]);
  u.h[2] = __float2bfloat16(a[2]); u.h[3] = __float2bfloat16(a[3]);
  u.h[4] = __float2bfloat16(b[0]); u.h[5] = __float2bfloat16(b[1]);
  u.h[6] = __float2bfloat16(b[2]); u.h[7] = __float2bfloat16(b[3]);
  ((short8*)dst)[i] = u.v;
}

// ---- prep: cvt(W) ONLY + scatter (no last pre-pass; ~12 MB total) ----
__global__ __launch_bounds__(256) void prep_kernel(
    const float* __restrict__ W, const int* __restrict__ vec,
    const int* __restrict__ child_l, const int* __restrict__ child_r,
    const int* __restrict__ drev, const int* __restrict__ dmap,
    int* __restrict__ ws) {
  __hip_bfloat16* W_bf = (__hip_bfloat16*)(ws + WS_W_OFF);
  int gid = blockIdx.x * 256 + threadIdx.x;
  if (gid < N_W8) {
    cvt8(W, W_bf, gid);
  } else {
    __shared__ int lcnt[8];
    __shared__ int gbase[8];
    int tid = threadIdx.x;
    if (tid < 8) lcnt[tid] = 0;
    __syncthreads();
    int lin = gid - N_W8;
    int l = lin & (LL - 1);
    int v = vec[lin];
    int dir = dmap[v] & 7;
    int sw = drev[v];
    int cl = child_l[l];
    int cr = child_r[l];
    int r0 = sw ? cr : cl;
    int r1 = sw ? cl : cr;
    int pos = atomicAdd(&lcnt[dir], 1);
    __syncthreads();
    if (tid < 8) gbase[tid] = lcnt[tid] ? atomicAdd(&ws[tid], lcnt[tid]) : 0;
    __syncthreads();
    int slot = dir * CAP + gbase[dir] + pos;
    ws[IDX_OFF + slot] = lin;
    ws[ROWS_OFF + slot] = r0 | (r1 << 16);
  }
}

// ---- grouped GEMM: 128x128 tile, BK=32, TWO sequential n-tiles per block --
// 4 waves (2m x 2n), each wave 64x64 via 4x4 mfma_f32_16x16x32_bf16.
// A staged as F32 directly from `last` (no pre-cvt pass): 3 x 16KB buffers,
// 2 chunks ahead, counted vmcnt — never drains. In-register f32->bf16 cvt.
// B read directly to REGISTERS from the L2-hot bf16 W copy, double-buffered
// 1 step ahead (counts in the same vmcnt FIFO). LDS 48KB -> 3 blocks/CU;
// 524 blocks all resident. Tile0's epilogue stores drain during tile1's
// K-loop (write burst overlapped); tile1's A-gather is L2/L3-warm.
// A LDS layout: [128 rows][32 f32], 16B-unit u stores global unit u^(row&7);
// lane-linear staging dest (global_load_lds), swizzle on the source address.
// Frag read = 2x ds_read_b128 at units u0, u0^1 (structural-minimum banking).
__global__ __launch_bounds__(256, 3) void gemm_kernel(
    const float* __restrict__ last, const float* __restrict__ bias,
    const float* __restrict__ alpha_m, const int* __restrict__ ws,
    float* __restrict__ out) {
  __shared__ float Als[3][128 * 32];  // 3 x 16 KB

  // bijective XCD swizzle (524 = 4 chunks of 66 + 4 of 65): both n-pairs of
  // neighboring m-tiles land on one XCD -> A shared in its L2.
  int flat = blockIdx.x;
  int xcd = flat & 7;
  int swz = (xcd < 4 ? xcd * 66 : 264 + (xcd - 4) * 65) + (flat >> 3);
  const int mt = swz >> 1;
  const int npair = swz & 1;

  // ---- tile -> dir mapping (counts = fill cursors at ws[0..7]) ----
  int d = -1, count = 0, m_base = 0;
  {
    int tb = 0;
    for (int dd = 0; dd < 8; ++dd) {
      int c = ws[dd];
      int ntile = (c + 127) >> 7;
      if (mt < tb + ntile) { d = dd; count = c; m_base = (mt - tb) * 128; break; }
      tb += ntile;
    }
  }
  if (d < 0) return;

  const int* idxA = ws + IDX_OFF + d * CAP;
  const int* rowsA = ws + ROWS_OFF + d * CAP;
  const char* W_bf = (const char*)(ws + WS_W_OFF);
  const char* lastc = (const char*)last;

  const int tid = threadIdx.x;
  const int wave = __builtin_amdgcn_readfirstlane(tid >> 6);
  const int lane = tid & 63;
  const int lane15 = lane & 15;
  const int quad = lane >> 4;
  const int wm = wave >> 1;
  const int wn = wave & 1;

  // ---- A staging descriptors: 4 instrs/wave, 8 rows each (f32 rows) ----
  // lane l: row = I*8 + (l>>3); LDS 16B-unit u = l&7 (linear dest);
  // global unit u' = u ^ (row&7) = (l&7)^(l>>3)  [I*8 == 0 mod 8].
  const char* ap0[4];
  const char* ap1[4];
  int ldsA[4];  // f32 elem offset of instr base
  {
    const int usw = ((lane & 7) ^ (lane >> 3)) * 16;  // swizzled byte in chunk
#pragma unroll
    for (int i = 0; i < 4; ++i) {
      const int I = wave * 4 + i;
      ldsA[i] = I * 256;  // 8 rows * 32 f32
      int row_local = I * 8 + (lane >> 3);
      int gr = m_base + row_local;
      if (gr >= count) gr = count - 1;  // clamp (tile exists => count>0)
      int lin = idxA[gr] & (TOT - 1);
      int rr = rowsA[gr];
      int b = lin >> 12;
      ap0[i] = lastc + (long long)(b * NCH + (rr & (NCH - 1))) * 1024 + usw;
      ap1[i] = lastc + (long long)(b * NCH + ((rr >> 16) & (NCH - 1))) * 1024 + usw;
    }
  }
  // ---- B fragment byte offsets (tt=0 base; tile1 adds 128*KDIM*2) ----
  int bo[4];
#pragma unroll
  for (int j = 0; j < 4; ++j)
    bo[j] = ((d * ODIM + npair * 256 + wn * 64 + j * 16 + lane15) * KDIM + quad * 8) * 2;

#define STAGE_A(c, buf)                                                  \
  {                                                                      \
    const int ko = ((c) & 7) * 128; /* 32 f32 per k-chunk */             \
    _Pragma("unroll") for (int i = 0; i < 4; ++i)                        \
        async_copy16(((c) < 8 ? ap0[i] : ap1[i]) + ko,                   \
                     &Als[(buf)][ldsA[i]]);                              \
  }
#define LOAD_B(c, buf, toff)                                             \
  {                                                                      \
    _Pragma("unroll") for (int j = 0; j < 4; ++j)                        \
        bR[(buf)][j] = *(const short8*)(W_bf + bo[j] + (toff) + (c) * 64); \
  }

  const int u0base = 2 * quad;  // frag k-units before row-XOR

#pragma unroll
  for (int tt = 0; tt < 2; ++tt) {
    const int toff = tt * (128 * KDIM * 2);
    floatx4 acc[4][4] = {};
    short8 bR[2][4];

    // tile-start barrier: all waves done READING Als from previous tile
    // before restaging buffer 0 (harmless for tt=0).
    __builtin_amdgcn_s_barrier();
    // prologue (oldest-first for FIFO vmcnt): B(0), A(0), A(1)
    LOAD_B(0, 0, toff);
    STAGE_A(0, 0);
    STAGE_A(1, 1);

#pragma unroll
    for (int c = 0; c < 16; ++c) {
      // barrier 1: all waves done reading Als[(c+2)%3] (= compute step c-1)
      __builtin_amdgcn_s_barrier();
      if (c < 15) LOAD_B(c + 1, (c + 1) & 1, toff);
      if (c < 14) STAGE_A(c + 2, (c + 2) % 3);
      // FIFO: need A(c),B(c) retired. Newer in flight:
      //   c<14:  B(c+1)4 + A(c+1)4 + A(c+2)4 = 12
      //   c==14: A(15)4 + B(15)4 = 8;   c==15: 0
      if (c < 14) {
        asm volatile("s_waitcnt vmcnt(12)" ::: "memory");
      } else if (c == 14) {
        asm volatile("s_waitcnt vmcnt(8)" ::: "memory");
      } else {
        asm volatile("s_waitcnt vmcnt(0)" ::: "memory");
      }
      __builtin_amdgcn_sched_barrier(0);
      // barrier 2: every wave's own-wait passed -> all A(c) rows visible
      __builtin_amdgcn_s_barrier();

      const float* Ab = Als[c % 3];
      short8 a[4];
#pragma unroll
      for (int i = 0; i < 4; ++i) {
        const int row = wm * 64 + i * 16 + lane15;
        const int u0 = u0base ^ (row & 7);
        const floatx4 f0 = *(const floatx4*)&Ab[row * 32 + u0 * 4];
        const floatx4 f1 = *(const floatx4*)&Ab[row * 32 + (u0 ^ 1) * 4];
        union { short8 v; __hip_bfloat16 h[8]; } u;
        u.h[0] = __float2bfloat16(f0[0]); u.h[1] = __float2bfloat16(f0[1]);
        u.h[2] = __float2bfloat16(f0[2]); u.h[3] = __float2bfloat16(f0[3]);
        u.h[4] = __float2bfloat16(f1[0]); u.h[5] = __float2bfloat16(f1[1]);
        u.h[6] = __float2bfloat16(f1[2]); u.h[7] = __float2bfloat16(f1[3]);
        a[i] = u.v;
      }
#pragma unroll
      for (int i = 0; i < 4; ++i)
#pragma unroll
        for (int j = 0; j < 4; ++j)
          acc[i][j] = __builtin_amdgcn_mfma_f32_16x16x32_bf16(
              a[i], bR[c & 1][j], acc[i][j], 0, 0, 0);
    }

    // ---- epilogue tt: bias + leaky relu, scatter rows (fire-and-forget;
    //      stores drain to HBM while the next tile's K-loop runs) ----
    const int n_col = npair * 256 + tt * 128 + wn * 64;
    const float alpha = alpha_m[d];
    float bj[4];
#pragma unroll
    for (int j = 0; j < 4; ++j)
      bj[j] = bias[d * ODIM + n_col + j * 16 + lane15];

#pragma unroll
    for (int i = 0; i < 4; ++i) {
#pragma unroll
      for (int reg = 0; reg < 4; ++reg) {
        int row_id = m_base + wm * 64 + i * 16 + quad * 4 + reg;
        if (row_id >= count) continue;
        int lin = idxA[row_id] & (TOT - 1);
        float* orow = out + (long long)lin * ODIM + n_col;
#pragma unroll
        for (int j = 0; j < 4; ++j) {
          float y = acc[i][j][reg] + bj[j];
          y = y > 0.f ? y : alpha * y;
          orow[j * 16 + lane15] = y;
        }
      }
    }
  }
}

extern "C" void kernel_launch(void* const* d_in, const int* in_sizes, int n_in,
                              void* d_out, int out_size, void* d_ws, size_t ws_size,
                              hipStream_t stream) {
  const float* last = (const float*)d_in[0];
  const float* W = (const float*)d_in[1];
  const float* bias = (const float*)d_in[2];
  const float* alpha = (const float*)d_in[3];
  const int* child_l = (const int*)d_in[4];
  const int* child_r = (const int*)d_in[5];
  const int* vec = (const int*)d_in[6];
  const int* drev = (const int*)d_in[7];
  const int* dmap = (const int*)d_in[8];

  int* ws = (int*)d_ws;

  hipMemsetAsync(ws, 0, 64 * sizeof(int), stream);
  // prep: W-cvt (768 blocks) + scatter (128 blocks)
  prep_kernel<<<(N_W8 / 256) + (TOT / 256), 256, 0, stream>>>(
      W, vec, child_l, child_r, drev, dmap, ws);
  gemm_kernel<<<NWG, 256, 0, stream>>>(last, bias, alpha, ws, (float*)d_out);
}